// Round 1
// baseline (791.685 us; speedup 1.0000x reference)
//
#include <hip/hip_runtime.h>
#include <hip/hip_bf16.h>

// Problem constants
#define B_   8192
#define SEQ_ 4
#define C_   1024
#define H_   16
#define D_   64
#define P_   4
#define M_   (B_ * SEQ_)   // 32768 rows
#define K_   1024
#define N1_  3072          // qkv GEMM cols
// SCALE = D^-0.5 = 0.125, folded into W_qkvT q-section

typedef __attribute__((ext_vector_type(8))) short short8;
typedef __attribute__((ext_vector_type(4))) float f32x4;

__device__ __forceinline__ unsigned short f2bf(float f) {
  union { float f; unsigned u; } v; v.f = f;
  unsigned r = v.u + 0x7fffu + ((v.u >> 16) & 1u);   // RNE
  return (unsigned short)(r >> 16);
}
__device__ __forceinline__ float bf2f(unsigned short u) {
  union { unsigned u; float f; } v; v.u = ((unsigned)u) << 16;
  return v.f;
}

// ---------------- cast fp32 -> bf16 (x4 vectorized, exact grid) ----------------
__global__ __launch_bounds__(256) void cast_bf16_k(const float* __restrict__ in,
                                                   unsigned short* __restrict__ out) {
  int i = blockIdx.x * 256 + threadIdx.x;
  float4 v = ((const float4*)in)[i];
  ushort4 o;
  o.x = f2bf(v.x); o.y = f2bf(v.y); o.z = f2bf(v.z); o.w = f2bf(v.w);
  ((ushort4*)out)[i] = o;
}

// ---------------- transpose + cast W_qkv [1024,3072] -> [3072,1024] bf16 -------
// Folds SCALE into rows j<1024 (the q section).
__global__ __launch_bounds__(256) void transpose_wqkv_k(const float* __restrict__ in,
                                                        unsigned short* __restrict__ out) {
  __shared__ float t[32][33];
  int tx = threadIdx.x, ty = threadIdx.y;          // block (32,8)
  int j0 = blockIdx.x * 32, c0 = blockIdx.y * 32;
#pragma unroll
  for (int i = 0; i < 4; ++i)
    t[ty + i * 8][tx] = in[(size_t)(c0 + ty + i * 8) * N1_ + j0 + tx];
  __syncthreads();
#pragma unroll
  for (int i = 0; i < 4; ++i) {
    int j = j0 + ty + i * 8;
    float v = t[tx][ty + i * 8];
    if (j < 1024) v *= 0.125f;                      // SCALE folded into q rows
    out[(size_t)j * K_ + c0 + tx] = f2bf(v);
  }
}

// ---------------- NT GEMM: C[m,n] = sum_k A[m,k]*B[n,k], bf16 in, fp32 acc -----
// 128x128 tile, BK=32, 256 threads (4 waves 2x2), mfma_f32_16x16x32_bf16,
// global_load_lds width=16 staging (m97 structure).
template <int OUTMODE>  // 0: bf16 C   1: fp32 C + bias
__global__ __launch_bounds__(256) void gemm_nt(const unsigned short* __restrict__ A,
                                               const unsigned short* __restrict__ Bm,
                                               unsigned short* __restrict__ Cbf,
                                               float* __restrict__ Cf,
                                               const float* __restrict__ bias,
                                               int K, int Ncols) {
  __shared__ unsigned short lsA[128 * 32];
  __shared__ unsigned short lsB[128 * 32];
  const int tid = threadIdx.x;
  const int wave = tid >> 6, lane = tid & 63;
  const int wm = (wave >> 1) * 64, wn = (wave & 1) * 64;
  const long tile_m = (long)blockIdx.y * 128, tile_n = (long)blockIdx.x * 128;

  f32x4 acc[4][4] = {};

  // staging: each wave fills two contiguous 1KB LDS chunks per tile
  const int ci0 = (wave * 2 + 0) * 64 + lane;
  const int ci1 = (wave * 2 + 1) * 64 + lane;
  const int r0 = ci0 >> 2, kc0 = (ci0 & 3) * 8;
  const int r1 = ci1 >> 2, kc1 = (ci1 & 3) * 8;
  const unsigned short* gA0 = A + (tile_m + r0) * K + kc0;
  const unsigned short* gA1 = A + (tile_m + r1) * K + kc1;
  const unsigned short* gB0 = Bm + (tile_n + r0) * K + kc0;
  const unsigned short* gB1 = Bm + (tile_n + r1) * K + kc1;
  unsigned short* dA0 = lsA + (wave * 2 + 0) * 512;
  unsigned short* dA1 = lsA + (wave * 2 + 1) * 512;
  unsigned short* dB0 = lsB + (wave * 2 + 0) * 512;
  unsigned short* dB1 = lsB + (wave * 2 + 1) * 512;

  const int r16 = lane & 15, q8 = (lane >> 4) * 8;

  for (int kt = 0; kt < K; kt += 32) {
    __builtin_amdgcn_global_load_lds((const __attribute__((address_space(1))) void*)(gA0 + kt),
                                     (__attribute__((address_space(3))) void*)dA0, 16, 0, 0);
    __builtin_amdgcn_global_load_lds((const __attribute__((address_space(1))) void*)(gA1 + kt),
                                     (__attribute__((address_space(3))) void*)dA1, 16, 0, 0);
    __builtin_amdgcn_global_load_lds((const __attribute__((address_space(1))) void*)(gB0 + kt),
                                     (__attribute__((address_space(3))) void*)dB0, 16, 0, 0);
    __builtin_amdgcn_global_load_lds((const __attribute__((address_space(1))) void*)(gB1 + kt),
                                     (__attribute__((address_space(3))) void*)dB1, 16, 0, 0);
    __syncthreads();   // compiler drains vmcnt before s_barrier

    short8 afr[4], bfr[4];
#pragma unroll
    for (int mi = 0; mi < 4; ++mi)
      afr[mi] = *(const short8*)&lsA[(wm + mi * 16 + r16) * 32 + q8];
#pragma unroll
    for (int ni = 0; ni < 4; ++ni)
      bfr[ni] = *(const short8*)&lsB[(wn + ni * 16 + r16) * 32 + q8];
#pragma unroll
    for (int mi = 0; mi < 4; ++mi)
#pragma unroll
      for (int ni = 0; ni < 4; ++ni)
        acc[mi][ni] = __builtin_amdgcn_mfma_f32_16x16x32_bf16(afr[mi], bfr[ni], acc[mi][ni], 0, 0, 0);
    __syncthreads();
  }

  // epilogue: C/D layout col=lane&15, row=(lane>>4)*4+r
  const int cl = lane & 15, rq = (lane >> 4) * 4;
#pragma unroll
  for (int mi = 0; mi < 4; ++mi)
#pragma unroll
    for (int ni = 0; ni < 4; ++ni) {
      long col = tile_n + wn + ni * 16 + cl;
      float bv = (OUTMODE == 1) ? bias[col] : 0.f;
#pragma unroll
      for (int r = 0; r < 4; ++r) {
        long row = tile_m + wm + mi * 16 + rq + r;
        if (OUTMODE == 0)
          Cbf[(size_t)row * Ncols + col] = f2bf(acc[mi][ni][r]);
        else
          Cf[(size_t)row * Ncols + col] = acc[mi][ni][r] + bv;
      }
    }
}

// ---------------- per-batch attention ------------------------------------------
// One block per b. qkv slice [4,3072] -> fp32 LDS [s][n][h][65-padded d].
// Phase 1: lane=d, wave handles 4 heads: E/F proj, reduced softmax, h_mid out.
// Phase 2: thread=(h,g): attn_sel sigmoid (padded LDS -> conflict-free).
__global__ __launch_bounds__(256) void attn_k(const unsigned short* __restrict__ qkv,
                                              const float* __restrict__ WE,
                                              const float* __restrict__ WF,
                                              unsigned short* __restrict__ hmid,
                                              float* __restrict__ attn_sel) {
  __shared__ float ls[12 * 16 * 65];   // [(s*4+n)*16+h]*65 + d  (49,920 B)
  const int b = blockIdx.x, tid = threadIdx.x;
  const size_t base = (size_t)b * 4 * N1_;

  for (int j = tid; j < 12288; j += 256) {
    int n = j / N1_;
    int col = j - n * N1_;
    int s = col >> 10;
    int hd = col & 1023;
    int h = hd >> 6, d = hd & 63;
    ls[((s * 4 + n) * 16 + h) * 65 + d] = bf2f(qkv[base + (size_t)n * N1_ + col]);
  }
  __syncthreads();

  const int lane = tid & 63, wave = tid >> 6;
  float we[16], wf[16];
#pragma unroll
  for (int i = 0; i < 16; ++i) { we[i] = WE[i]; wf[i] = WF[i]; }

#pragma unroll
  for (int hi = 0; hi < 4; ++hi) {
    int h = wave * 4 + hi;
    float qv[4], kv[4], vv[4];
#pragma unroll
    for (int n = 0; n < 4; ++n) {
      qv[n] = ls[((0 + n) * 16 + h) * 65 + lane];
      kv[n] = ls[((4 + n) * 16 + h) * 65 + lane];
      vv[n] = ls[((8 + n) * 16 + h) * 65 + lane];
    }
    float kl[4], vl[4];
#pragma unroll
    for (int p = 0; p < 4; ++p) {
      kl[p] = kv[0] * we[p * 4] + kv[1] * we[p * 4 + 1] + kv[2] * we[p * 4 + 2] + kv[3] * we[p * 4 + 3];
      vl[p] = vv[0] * wf[p * 4] + vv[1] * wf[p * 4 + 1] + vv[2] * wf[p * 4 + 2] + vv[3] * wf[p * 4 + 3];
    }
    float lg[4][4];
#pragma unroll
    for (int n = 0; n < 4; ++n)
#pragma unroll
      for (int p = 0; p < 4; ++p) lg[n][p] = qv[n] * kl[p];
    // butterfly reduce over d (64 lanes)
#pragma unroll
    for (int off = 1; off < 64; off <<= 1)
#pragma unroll
      for (int n = 0; n < 4; ++n)
#pragma unroll
        for (int p = 0; p < 4; ++p) lg[n][p] += __shfl_xor(lg[n][p], off, 64);

#pragma unroll
    for (int n = 0; n < 4; ++n) {
      float mx = fmaxf(fmaxf(lg[n][0], lg[n][1]), fmaxf(lg[n][2], lg[n][3]));
      float e0 = __expf(lg[n][0] - mx), e1 = __expf(lg[n][1] - mx);
      float e2 = __expf(lg[n][2] - mx), e3 = __expf(lg[n][3] - mx);
      float inv = 1.f / (e0 + e1 + e2 + e3);
      float o = (e0 * vl[0] + e1 * vl[1] + e2 * vl[2] + e3 * vl[3]) * inv;
      hmid[((size_t)b * 4 + n) * C_ + h * 64 + lane] = f2bf(o);
    }
  }

  // attn_sel[b,h,g] = sigmoid( q[h, n=1, :] . k[g, n=2, :] )   (q pre-scaled)
  const int h2 = tid >> 4, g = tid & 15;
  const float* qrow = &ls[((0 + 1) * 16 + h2) * 65];    // s=0, n=1
  const float* krow = &ls[((4 + 2) * 16 + g) * 65];     // s=1, n=2
  float acc = 0.f;
#pragma unroll 8
  for (int d = 0; d < 64; ++d) acc += qrow[d] * krow[d];
  attn_sel[(size_t)b * 256 + tid] = 1.f / (1.f + __expf(-acc));
}

// ---------------- launch --------------------------------------------------------
extern "C" void kernel_launch(void* const* d_in, const int* in_sizes, int n_in,
                              void* d_out, int out_size, void* d_ws, size_t ws_size,
                              hipStream_t stream) {
  (void)in_sizes; (void)n_in; (void)out_size; (void)ws_size;
  const float* x      = (const float*)d_in[0];
  const float* W_qkv  = (const float*)d_in[1];
  const float* W_proj = (const float*)d_in[2];
  const float* b_proj = (const float*)d_in[3];
  const float* W_E    = (const float*)d_in[4];
  const float* W_F    = (const float*)d_in[5];

  float* out0 = (float*)d_out;                       // [B,N,C] fp32
  float* out1 = out0 + (size_t)M_ * C_;              // [B,H,H] fp32

  char* ws = (char*)d_ws;
  unsigned short* x_bf   = (unsigned short*)(ws);                 // 67,108,864 B
  unsigned short* wqkvT  = (unsigned short*)(ws + 67108864);      //  6,291,456 B
  unsigned short* wproj  = (unsigned short*)(ws + 73400320);      //  2,097,152 B
  unsigned short* qkv_bf = (unsigned short*)(ws + 75497472);      // 201,326,592 B
  unsigned short* hmid   = x_bf;                                  // alias: x dead after GEMM1

  // 1) casts / transpose
  cast_bf16_k<<<(M_ * C_) / 1024, 256, 0, stream>>>(x, x_bf);
  transpose_wqkv_k<<<dim3(N1_ / 32, C_ / 32), dim3(32, 8), 0, stream>>>(W_qkv, wqkvT);
  cast_bf16_k<<<(C_ * C_) / 1024, 256, 0, stream>>>(W_proj, wproj);

  // 2) qkv = x @ W_qkv  (NT with pre-transposed W)  -> bf16 [32768, 3072]
  gemm_nt<0><<<dim3(N1_ / 128, M_ / 128), 256, 0, stream>>>(x_bf, wqkvT, qkv_bf, nullptr,
                                                            nullptr, K_, N1_);
  // 3) attention per b -> hmid bf16 [32768,1024], attn_sel fp32
  attn_k<<<B_, 256, 0, stream>>>(qkv_bf, W_E, W_F, hmid, out1);

  // 4) out = hmid @ W_proj^T + b  -> fp32 [32768,1024]
  gemm_nt<1><<<dim3(C_ / 128, M_ / 128), 256, 0, stream>>>(hmid, wproj, nullptr, out0,
                                                           b_proj, K_, C_);
}

// Round 2
// 662.882 us; speedup vs baseline: 1.1943x; 1.1943x over previous
//
#include <hip/hip_runtime.h>
#include <hip/hip_bf16.h>

// Problem constants
#define B_   8192
#define SEQ_ 4
#define C_   1024
#define H_   16
#define D_   64
#define P_   4
#define M_   (B_ * SEQ_)   // 32768 rows
#define K_   1024
#define N1_  3072          // qkv GEMM cols
// SCALE = D^-0.5 = 0.125, folded into W_qkvT q-section

typedef __attribute__((ext_vector_type(8))) short short8;
typedef __attribute__((ext_vector_type(4))) float f32x4;

__device__ __forceinline__ unsigned short f2bf(float f) {
  union { float f; unsigned u; } v; v.f = f;
  unsigned r = v.u + 0x7fffu + ((v.u >> 16) & 1u);   // RNE
  return (unsigned short)(r >> 16);
}
__device__ __forceinline__ float bf2f(unsigned short u) {
  union { unsigned u; float f; } v; v.u = ((unsigned)u) << 16;
  return v.f;
}

// ---------------- cast fp32 -> bf16 (x4 vectorized, exact grid) ----------------
__global__ __launch_bounds__(256) void cast_bf16_k(const float* __restrict__ in,
                                                   unsigned short* __restrict__ out) {
  int i = blockIdx.x * 256 + threadIdx.x;
  float4 v = ((const float4*)in)[i];
  ushort4 o;
  o.x = f2bf(v.x); o.y = f2bf(v.y); o.z = f2bf(v.z); o.w = f2bf(v.w);
  ((ushort4*)out)[i] = o;
}

// ---------------- transpose + cast W_qkv [1024,3072] -> [3072,1024] bf16 -------
// Folds SCALE into rows j<1024 (the q section).
__global__ __launch_bounds__(256) void transpose_wqkv_k(const float* __restrict__ in,
                                                        unsigned short* __restrict__ out) {
  __shared__ float t[32][33];
  int tx = threadIdx.x, ty = threadIdx.y;          // block (32,8)
  int j0 = blockIdx.x * 32, c0 = blockIdx.y * 32;
#pragma unroll
  for (int i = 0; i < 4; ++i)
    t[ty + i * 8][tx] = in[(size_t)(c0 + ty + i * 8) * N1_ + j0 + tx];
  __syncthreads();
#pragma unroll
  for (int i = 0; i < 4; ++i) {
    int j = j0 + ty + i * 8;
    float v = t[tx][ty + i * 8];
    if (j < 1024) v *= 0.125f;                      // SCALE folded into q rows
    out[(size_t)j * K_ + c0 + tx] = f2bf(v);
  }
}

// ---------------- NT GEMM: C[m,n] = sum_k A[m,k]*B[n,k], bf16 in, fp32 acc -----
// 128x128 tile, BK=32, 256 threads (4 waves 2x2), mfma_f32_16x16x32_bf16,
// global_load_lds width=16 staging (m97 structure).
template <int OUTMODE>  // 0: bf16 C   1: fp32 C + bias
__global__ __launch_bounds__(256) void gemm_nt(const unsigned short* __restrict__ A,
                                               const unsigned short* __restrict__ Bm,
                                               unsigned short* __restrict__ Cbf,
                                               float* __restrict__ Cf,
                                               const float* __restrict__ bias,
                                               int K, int Ncols) {
  __shared__ unsigned short lsA[128 * 32];
  __shared__ unsigned short lsB[128 * 32];
  const int tid = threadIdx.x;
  const int wave = tid >> 6, lane = tid & 63;
  const int wm = (wave >> 1) * 64, wn = (wave & 1) * 64;
  const long tile_m = (long)blockIdx.y * 128, tile_n = (long)blockIdx.x * 128;

  f32x4 acc[4][4] = {};

  // staging: each wave fills two contiguous 1KB LDS chunks per tile
  const int ci0 = (wave * 2 + 0) * 64 + lane;
  const int ci1 = (wave * 2 + 1) * 64 + lane;
  const int r0 = ci0 >> 2, kc0 = (ci0 & 3) * 8;
  const int r1 = ci1 >> 2, kc1 = (ci1 & 3) * 8;
  const unsigned short* gA0 = A + (tile_m + r0) * K + kc0;
  const unsigned short* gA1 = A + (tile_m + r1) * K + kc1;
  const unsigned short* gB0 = Bm + (tile_n + r0) * K + kc0;
  const unsigned short* gB1 = Bm + (tile_n + r1) * K + kc1;
  unsigned short* dA0 = lsA + (wave * 2 + 0) * 512;
  unsigned short* dA1 = lsA + (wave * 2 + 1) * 512;
  unsigned short* dB0 = lsB + (wave * 2 + 0) * 512;
  unsigned short* dB1 = lsB + (wave * 2 + 1) * 512;

  const int r16 = lane & 15, q8 = (lane >> 4) * 8;

  for (int kt = 0; kt < K; kt += 32) {
    __builtin_amdgcn_global_load_lds((const __attribute__((address_space(1))) void*)(gA0 + kt),
                                     (__attribute__((address_space(3))) void*)dA0, 16, 0, 0);
    __builtin_amdgcn_global_load_lds((const __attribute__((address_space(1))) void*)(gA1 + kt),
                                     (__attribute__((address_space(3))) void*)dA1, 16, 0, 0);
    __builtin_amdgcn_global_load_lds((const __attribute__((address_space(1))) void*)(gB0 + kt),
                                     (__attribute__((address_space(3))) void*)dB0, 16, 0, 0);
    __builtin_amdgcn_global_load_lds((const __attribute__((address_space(1))) void*)(gB1 + kt),
                                     (__attribute__((address_space(3))) void*)dB1, 16, 0, 0);
    __syncthreads();   // compiler drains vmcnt before s_barrier

    short8 afr[4], bfr[4];
#pragma unroll
    for (int mi = 0; mi < 4; ++mi)
      afr[mi] = *(const short8*)&lsA[(wm + mi * 16 + r16) * 32 + q8];
#pragma unroll
    for (int ni = 0; ni < 4; ++ni)
      bfr[ni] = *(const short8*)&lsB[(wn + ni * 16 + r16) * 32 + q8];
#pragma unroll
    for (int mi = 0; mi < 4; ++mi)
#pragma unroll
      for (int ni = 0; ni < 4; ++ni)
        acc[mi][ni] = __builtin_amdgcn_mfma_f32_16x16x32_bf16(afr[mi], bfr[ni], acc[mi][ni], 0, 0, 0);
    __syncthreads();
  }

  // epilogue: C/D layout col=lane&15, row=(lane>>4)*4+r
  const int cl = lane & 15, rq = (lane >> 4) * 4;
#pragma unroll
  for (int mi = 0; mi < 4; ++mi)
#pragma unroll
    for (int ni = 0; ni < 4; ++ni) {
      long col = tile_n + wn + ni * 16 + cl;
      float bv = (OUTMODE == 1) ? bias[col] : 0.f;
#pragma unroll
      for (int r = 0; r < 4; ++r) {
        long row = tile_m + wm + mi * 16 + rq + r;
        if (OUTMODE == 0)
          Cbf[(size_t)row * Ncols + col] = f2bf(acc[mi][ni][r]);
        else
          Cf[(size_t)row * Ncols + col] = acc[mi][ni][r] + bv;
      }
    }
}

// ---------------- MFMA attention: 1 wave = 1 batch element ----------------------
// Per b:  C[n][m] = q_n . k_m^T over all 16 heads as 16x16 MFMA products (K=64).
//   * diag of C[n][m]  -> S[h][n,m]  (Linformer logits: logits = S . WE^T)
//   * full  C[1][2]    -> attn_sel (sigmoid)  [free: same MFMA set]
// Then softmax + A' = attn.WF on the 16 diagonal lanes, broadcast A' via LDS,
// and out[h,n,:] = sum_m A'[n,m] * v[h,m,:] with vectorized loads/stores.
__global__ __launch_bounds__(256) void attn_mfma_k(const unsigned short* __restrict__ qkv,
                                                   const float* __restrict__ WE,
                                                   const float* __restrict__ WF,
                                                   unsigned short* __restrict__ hmid,
                                                   float* __restrict__ attn_sel) {
  __shared__ float As[4][16 * 17 + 2];   // per-wave A' broadcast, pad 17 (conflict-free)
  const int tid = threadIdx.x;
  const int wave = tid >> 6, lane = tid & 63;
  const int b = blockIdx.x * 4 + wave;
  const size_t qb = (size_t)b * 4 * N1_;

  const int hl = lane & 15;        // A/B fragment row = head
  const int qg = lane >> 4;        // k-subchunk group

  // ---- 32 MFMAs: accS[n][m] = q_n (16 heads x 64) . k_m^T ----
  f32x4 accS[4][4] = {};
#pragma unroll
  for (int ch = 0; ch < 2; ++ch) {
    const int off = ch * 32 + qg * 8;
    short8 qf[4], kf[4];
#pragma unroll
    for (int n = 0; n < 4; ++n)
      qf[n] = *(const short8*)(qkv + qb + (size_t)n * N1_ + 0 + hl * 64 + off);
#pragma unroll
    for (int m = 0; m < 4; ++m)
      kf[m] = *(const short8*)(qkv + qb + (size_t)m * N1_ + 1024 + hl * 64 + off);
#pragma unroll
    for (int n = 0; n < 4; ++n)
#pragma unroll
      for (int m = 0; m < 4; ++m)
        accS[n][m] = __builtin_amdgcn_mfma_f32_16x16x32_bf16(qf[n], kf[m], accS[n][m], 0, 0, 0);
  }

  // ---- attn_sel = sigmoid(C[1][2]) : C layout col=lane&15, row=qg*4+r ----
#pragma unroll
  for (int r = 0; r < 4; ++r) {
    float t = accS[1][2][r];
    attn_sel[(size_t)b * 256 + (qg * 4 + r) * 16 + hl] = 1.f / (1.f + __expf(-t));
  }

  // ---- diagonal lanes: full per-head softmax + A' = softmax(S.WE^T).WF ----
  // lane holds C[row=qg*4+r][col=hl]; diag (row==col) lives on lanes with hl>>2==qg.
  if ((hl >> 2) == qg) {
    const int h = hl, rr = h & 3;
    float Sm[4][4];
#pragma unroll
    for (int n = 0; n < 4; ++n)
#pragma unroll
      for (int m = 0; m < 4; ++m) Sm[n][m] = accS[n][m][rr];
#pragma unroll
    for (int n = 0; n < 4; ++n) {
      float lg[4];
#pragma unroll
      for (int p = 0; p < 4; ++p)
        lg[p] = Sm[n][0] * WE[p * 4] + Sm[n][1] * WE[p * 4 + 1] +
                Sm[n][2] * WE[p * 4 + 2] + Sm[n][3] * WE[p * 4 + 3];
      float mx = fmaxf(fmaxf(lg[0], lg[1]), fmaxf(lg[2], lg[3]));
      float e0 = __expf(lg[0] - mx), e1 = __expf(lg[1] - mx);
      float e2 = __expf(lg[2] - mx), e3 = __expf(lg[3] - mx);
      float inv = 1.f / (e0 + e1 + e2 + e3);
      e0 *= inv; e1 *= inv; e2 *= inv; e3 *= inv;
#pragma unroll
      for (int m = 0; m < 4; ++m)
        As[wave][h * 17 + n * 4 + m] =
            e0 * WF[0 * 4 + m] + e1 * WF[1 * 4 + m] + e2 * WF[2 * 4 + m] + e3 * WF[3 * 4 + m];
    }
  }
  __syncthreads();

  // ---- out[h,n,d] = sum_m A'[n,m] * v[h,m,d]; lane = (dg, h) ----
  {
    const int h = lane & 15, dg = lane >> 4;   // dg: 16-wide d group
    float Ap[4][4];
#pragma unroll
    for (int n = 0; n < 4; ++n)
#pragma unroll
      for (int m = 0; m < 4; ++m) Ap[n][m] = As[wave][h * 17 + n * 4 + m];

    float outv[4][16] = {};
#pragma unroll
    for (int m = 0; m < 4; ++m) {
      const unsigned short* vp = qkv + qb + (size_t)m * N1_ + 2048 + h * 64 + dg * 16;
      short8 v0 = *(const short8*)(vp);
      short8 v1 = *(const short8*)(vp + 8);
      float vf[16];
#pragma unroll
      for (int j = 0; j < 8; ++j) {
        vf[j] = bf2f((unsigned short)v0[j]);
        vf[8 + j] = bf2f((unsigned short)v1[j]);
      }
#pragma unroll
      for (int n = 0; n < 4; ++n)
#pragma unroll
        for (int d = 0; d < 16; ++d) outv[n][d] += Ap[n][m] * vf[d];
    }
#pragma unroll
    for (int n = 0; n < 4; ++n) {
      short8 o0, o1;
#pragma unroll
      for (int j = 0; j < 8; ++j) {
        o0[j] = (short)f2bf(outv[n][j]);
        o1[j] = (short)f2bf(outv[n][8 + j]);
      }
      unsigned short* op = hmid + ((size_t)b * 4 + n) * C_ + h * 64 + dg * 16;
      *(short8*)(op) = o0;
      *(short8*)(op + 8) = o1;
    }
  }
}

// ---------------- launch --------------------------------------------------------
extern "C" void kernel_launch(void* const* d_in, const int* in_sizes, int n_in,
                              void* d_out, int out_size, void* d_ws, size_t ws_size,
                              hipStream_t stream) {
  (void)in_sizes; (void)n_in; (void)out_size; (void)ws_size;
  const float* x      = (const float*)d_in[0];
  const float* W_qkv  = (const float*)d_in[1];
  const float* W_proj = (const float*)d_in[2];
  const float* b_proj = (const float*)d_in[3];
  const float* W_E    = (const float*)d_in[4];
  const float* W_F    = (const float*)d_in[5];

  float* out0 = (float*)d_out;                       // [B,N,C] fp32
  float* out1 = out0 + (size_t)M_ * C_;              // [B,H,H] fp32

  char* ws = (char*)d_ws;
  unsigned short* x_bf   = (unsigned short*)(ws);                 // 67,108,864 B
  unsigned short* wqkvT  = (unsigned short*)(ws + 67108864);      //  6,291,456 B
  unsigned short* wproj  = (unsigned short*)(ws + 73400320);      //  2,097,152 B
  unsigned short* qkv_bf = (unsigned short*)(ws + 75497472);      // 201,326,592 B
  unsigned short* hmid   = x_bf;                                  // alias: x dead after GEMM1

  // 1) casts / transpose
  cast_bf16_k<<<(M_ * C_) / 1024, 256, 0, stream>>>(x, x_bf);
  transpose_wqkv_k<<<dim3(N1_ / 32, C_ / 32), dim3(32, 8), 0, stream>>>(W_qkv, wqkvT);
  cast_bf16_k<<<(C_ * C_) / 1024, 256, 0, stream>>>(W_proj, wproj);

  // 2) qkv = x @ W_qkv  (NT with pre-transposed W)  -> bf16 [32768, 3072]
  gemm_nt<0><<<dim3(N1_ / 128, M_ / 128), 256, 0, stream>>>(x_bf, wqkvT, qkv_bf, nullptr,
                                                            nullptr, K_, N1_);
  // 3) attention: 1 wave per b -> hmid bf16 [32768,1024], attn_sel fp32
  attn_mfma_k<<<B_ / 4, 256, 0, stream>>>(qkv_bf, W_E, W_F, hmid, out1);

  // 4) out = hmid @ W_proj^T + b  -> fp32 [32768,1024]
  gemm_nt<1><<<dim3(C_ / 128, M_ / 128), 256, 0, stream>>>(hmid, wproj, nullptr, out0,
                                                           b_proj, K_, C_);
}

// Round 3
// 577.350 us; speedup vs baseline: 1.3712x; 1.1481x over previous
//
#include <hip/hip_runtime.h>
#include <hip/hip_bf16.h>

// Problem constants
#define B_   8192
#define C_   1024
#define H_   16
#define M_   (B_ * 4)      // 32768 rows
#define K_   1024
#define N1_  3072          // qkv GEMM cols
// SCALE = 0.125 folded into W_qkvT q-section. fp8 weights pre-scaled x32,
// compensated by MX scale byte 122 (=2^-5).

typedef __attribute__((ext_vector_type(8))) short short8;
typedef __attribute__((ext_vector_type(4))) float f32x4;
typedef __attribute__((ext_vector_type(8))) int   int8v;

__device__ __forceinline__ unsigned short f2bf(float f) {
  union { float f; unsigned u; } v; v.f = f;
  unsigned r = v.u + 0x7fffu + ((v.u >> 16) & 1u);   // RNE
  return (unsigned short)(r >> 16);
}
__device__ __forceinline__ float bf2f(unsigned short u) {
  union { unsigned u; float f; } v; v.u = ((unsigned)u) << 16;
  return v.f;
}
__device__ __forceinline__ int pk_fp8(float a, float b, float c, float d) {
  int r = __builtin_amdgcn_cvt_pk_fp8_f32(a, b, 0, false);
  r = __builtin_amdgcn_cvt_pk_fp8_f32(c, d, r, true);
  return r;
}

// ---- cast x: fp8 (scale 1.0) for GEMM1  +  bf16 rows n in {1,2} for fixup ----
__global__ __launch_bounds__(256) void cast_x_k(const float* __restrict__ x,
                                                unsigned char* __restrict__ x8,
                                                unsigned short* __restrict__ xsel) {
  const int row = blockIdx.x;               // 32768 rows (b*4+n)
  const int tid = threadIdx.x;
  float4 v = ((const float4*)(x + (size_t)row * 1024))[tid];
  ((int*)(x8 + (size_t)row * 1024))[tid] = pk_fp8(v.x, v.y, v.z, v.w);
  const int n = row & 3;
  if (n == 1 || n == 2) {                   // wave-uniform branch (per row)
    ushort4 o;
    o.x = f2bf(v.x); o.y = f2bf(v.y); o.z = f2bf(v.z); o.w = f2bf(v.w);
    ((ushort4*)(xsel + ((size_t)(n - 1) * 8192 + (row >> 2)) * 1024))[tid] = o;
  }
}

// ---- transpose W_qkv [1024,3072] -> [3072,1024]: bf16 (fixup B) + fp8 x32 ----
__global__ __launch_bounds__(256) void transpose_wqkv_k(const float* __restrict__ in,
                                                        unsigned short* __restrict__ outb,
                                                        unsigned char* __restrict__ out8) {
  __shared__ float t[32][33];
  int tx = threadIdx.x, ty = threadIdx.y;   // block (32,8)
  int j0 = blockIdx.x * 32, c0 = blockIdx.y * 32;
#pragma unroll
  for (int i = 0; i < 4; ++i)
    t[ty + i * 8][tx] = in[(size_t)(c0 + ty + i * 8) * N1_ + j0 + tx];
  __syncthreads();
#pragma unroll
  for (int i = 0; i < 4; ++i) {
    int j = j0 + ty + i * 8;
    float v = t[tx][ty + i * 8];
    if (j < 1024) v *= 0.125f;              // SCALE folded into q rows
    outb[(size_t)j * K_ + c0 + tx] = f2bf(v);
    out8[(size_t)j * K_ + c0 + tx] =
        (unsigned char)(__builtin_amdgcn_cvt_pk_fp8_f32(v * 32.f, v * 32.f, 0, false) & 0xff);
  }
}

// ---- cast W_proj -> fp8 x32 (no transpose: NT GEMM uses W rows as-is) --------
__global__ __launch_bounds__(256) void cast_wproj_k(const float* __restrict__ in,
                                                    unsigned char* __restrict__ out) {
  int i = blockIdx.x * 256 + threadIdx.x;
  float4 v = ((const float4*)in)[i];
  ((int*)out)[i] = pk_fp8(v.x * 32.f, v.y * 32.f, v.z * 32.f, v.w * 32.f);
}

// ---- bf16 NT GEMM (m97 structure) for the attn_sel fixup rows ----------------
// A = xsel [16384,1024]; rows <8192 use Wq section, >=8192 use Wk section.
__global__ __launch_bounds__(256) void gemm_fixup(const unsigned short* __restrict__ A,
                                                  const unsigned short* __restrict__ B0,
                                                  unsigned short* __restrict__ Cbf) {
  __shared__ unsigned short lsA[128 * 32];
  __shared__ unsigned short lsB[128 * 32];
  const int K = 1024, Ncols = 1024;
  const int tid = threadIdx.x;
  const int wave = tid >> 6, lane = tid & 63;
  const int wm = (wave >> 1) * 64, wn = (wave & 1) * 64;
  const long tile_m = (long)blockIdx.y * 128, tile_n = (long)blockIdx.x * 128;
  const unsigned short* Bm = B0 + (tile_m >= 8192 ? (size_t)1024 * 1024 : 0);

  f32x4 acc[4][4] = {};
  const int ci0 = (wave * 2 + 0) * 64 + lane;
  const int ci1 = (wave * 2 + 1) * 64 + lane;
  const int r0 = ci0 >> 2, kc0 = (ci0 & 3) * 8;
  const int r1 = ci1 >> 2, kc1 = (ci1 & 3) * 8;
  const unsigned short* gA0 = A + (tile_m + r0) * K + kc0;
  const unsigned short* gA1 = A + (tile_m + r1) * K + kc1;
  const unsigned short* gB0 = Bm + (tile_n + r0) * K + kc0;
  const unsigned short* gB1 = Bm + (tile_n + r1) * K + kc1;
  unsigned short* dA0 = lsA + (wave * 2 + 0) * 512;
  unsigned short* dA1 = lsA + (wave * 2 + 1) * 512;
  unsigned short* dB0 = lsB + (wave * 2 + 0) * 512;
  unsigned short* dB1 = lsB + (wave * 2 + 1) * 512;
  const int r16 = lane & 15, q8 = (lane >> 4) * 8;

  for (int kt = 0; kt < K; kt += 32) {
    __builtin_amdgcn_global_load_lds((const __attribute__((address_space(1))) void*)(gA0 + kt),
                                     (__attribute__((address_space(3))) void*)dA0, 16, 0, 0);
    __builtin_amdgcn_global_load_lds((const __attribute__((address_space(1))) void*)(gA1 + kt),
                                     (__attribute__((address_space(3))) void*)dA1, 16, 0, 0);
    __builtin_amdgcn_global_load_lds((const __attribute__((address_space(1))) void*)(gB0 + kt),
                                     (__attribute__((address_space(3))) void*)dB0, 16, 0, 0);
    __builtin_amdgcn_global_load_lds((const __attribute__((address_space(1))) void*)(gB1 + kt),
                                     (__attribute__((address_space(3))) void*)dB1, 16, 0, 0);
    __syncthreads();
    short8 afr[4], bfr[4];
#pragma unroll
    for (int mi = 0; mi < 4; ++mi)
      afr[mi] = *(const short8*)&lsA[(wm + mi * 16 + r16) * 32 + q8];
#pragma unroll
    for (int ni = 0; ni < 4; ++ni)
      bfr[ni] = *(const short8*)&lsB[(wn + ni * 16 + r16) * 32 + q8];
#pragma unroll
    for (int mi = 0; mi < 4; ++mi)
#pragma unroll
      for (int ni = 0; ni < 4; ++ni)
        acc[mi][ni] = __builtin_amdgcn_mfma_f32_16x16x32_bf16(afr[mi], bfr[ni], acc[mi][ni], 0, 0, 0);
    __syncthreads();
  }
  const int cl = lane & 15, rq = (lane >> 4) * 4;
#pragma unroll
  for (int mi = 0; mi < 4; ++mi)
#pragma unroll
    for (int ni = 0; ni < 4; ++ni) {
      long col = tile_n + wn + ni * 16 + cl;
#pragma unroll
      for (int r = 0; r < 4; ++r) {
        long row = tile_m + wm + mi * 16 + rq + r;
        Cbf[(size_t)row * Ncols + col] = f2bf(acc[mi][ni][r]);
      }
    }
}

// ---- MX-fp8 NT GEMM: C[m,n] = (2^(sA-127))(2^(sB-127)) sum_k A[m,k]B[n,k] ----
// 128x128 tile, BK=128, mfma_scale_f32_16x16x128_f8f6f4, fp8 e4m3.
// LDS layout: k-major [qg=4][4KB] with XOR swizzle (bank-2-way => free):
//   chunk(qg,row,half) at 16B-index qg*256 + bits{half^r0, r0^r2, r1^r3, r2, r3, row[6:4]}
// Staging scatters on the GLOBAL side only; LDS side stays base+lane*16.
template <int OUTMODE>  // 0: bf16 C   1: fp32 C + bias
__global__ __launch_bounds__(256) void gemm_mx(const unsigned char* __restrict__ A,
                                               const unsigned char* __restrict__ Bm,
                                               unsigned short* __restrict__ Cbf,
                                               float* __restrict__ Cf,
                                               const float* __restrict__ bias,
                                               int K, int Ncols, int sA, int sB) {
  __shared__ unsigned char lsA[16384];
  __shared__ unsigned char lsB[16384];
  const int tid = threadIdx.x;
  const int wave = tid >> 6, lane = tid & 63;
  const int wm = (wave >> 1) * 64, wn = (wave & 1) * 64;
  const long tile_m = (long)blockIdx.y * 128, tile_n = (long)blockIdx.x * 128;

  f32x4 acc[4][4] = {};

  // staging: 4 A-chunks + 4 B-chunks of 16B per thread per k-iter
  size_t offA[4], offB[4];
#pragma unroll
  for (int j = 0; j < 4; ++j) {
    int ci = j * 256 + tid;
    int qg = ci >> 8, id = ci & 255;
    int r2 = (id >> 3) & 1, r3 = (id >> 4) & 1;
    int rr0 = ((id >> 1) & 1) ^ r2, rr1 = ((id >> 2) & 1) ^ r3;
    int row = rr0 | (rr1 << 1) | (r2 << 2) | (r3 << 3) | ((id >> 5) << 4);
    int half = (id & 1) ^ rr0;
    offA[j] = (size_t)(tile_m + row) * K + qg * 32 + half * 16;
    offB[j] = (size_t)(tile_n + row) * K + qg * 32 + half * 16;
  }

  const int hl = lane & 15, qg = lane >> 4;
  const int swz = (hl & 12) << 3;
  const int laneFragBase = qg * 4096 + ((hl * 32) ^ swz) + ((hl & 1) << 4);

  for (int kt = 0; kt < K; kt += 128) {
#pragma unroll
    for (int j = 0; j < 4; ++j) {
      __builtin_amdgcn_global_load_lds(
          (const __attribute__((address_space(1))) void*)(A + offA[j] + kt),
          (__attribute__((address_space(3))) void*)(lsA + (j * 256 + wave * 64) * 16), 16, 0, 0);
      __builtin_amdgcn_global_load_lds(
          (const __attribute__((address_space(1))) void*)(Bm + offB[j] + kt),
          (__attribute__((address_space(3))) void*)(lsB + (j * 256 + wave * 64) * 16), 16, 0, 0);
    }
    __syncthreads();

    int8v af[4], bfr[4];
#pragma unroll
    for (int mi = 0; mi < 4; ++mi) {
      int ad = (wm + mi * 16) * 32 + laneFragBase;
      int4 h0 = *(const int4*)(lsA + ad);
      int4 h1 = *(const int4*)(lsA + (ad ^ 16));
      af[mi] = int8v{h0.x, h0.y, h0.z, h0.w, h1.x, h1.y, h1.z, h1.w};
    }
#pragma unroll
    for (int ni = 0; ni < 4; ++ni) {
      int ad = (wn + ni * 16) * 32 + laneFragBase;
      int4 h0 = *(const int4*)(lsB + ad);
      int4 h1 = *(const int4*)(lsB + (ad ^ 16));
      bfr[ni] = int8v{h0.x, h0.y, h0.z, h0.w, h1.x, h1.y, h1.z, h1.w};
    }
#pragma unroll
    for (int mi = 0; mi < 4; ++mi)
#pragma unroll
      for (int ni = 0; ni < 4; ++ni)
        acc[mi][ni] = __builtin_amdgcn_mfma_scale_f32_16x16x128_f8f6f4(
            af[mi], bfr[ni], acc[mi][ni], 0, 0, 0, sA, 0, sB);
    __syncthreads();
  }

  const int cl = lane & 15, rq = (lane >> 4) * 4;
#pragma unroll
  for (int mi = 0; mi < 4; ++mi)
#pragma unroll
    for (int ni = 0; ni < 4; ++ni) {
      long col = tile_n + wn + ni * 16 + cl;
      float bv = (OUTMODE == 1) ? bias[col] : 0.f;
#pragma unroll
      for (int r = 0; r < 4; ++r) {
        long row = tile_m + wm + mi * 16 + rq + r;
        if (OUTMODE == 0)
          Cbf[(size_t)row * Ncols + col] = f2bf(acc[mi][ni][r]);
        else
          Cf[(size_t)row * Ncols + col] = acc[mi][ni][r] + bv;
      }
    }
}

// ---- MFMA attention: 1 wave = 1 batch; attn_sel from accurate bf16 q1/k2 -----
__global__ __launch_bounds__(256) void attn_mfma_k(const unsigned short* __restrict__ qkv,
                                                   const unsigned short* __restrict__ q1,
                                                   const unsigned short* __restrict__ k2,
                                                   const float* __restrict__ WE,
                                                   const float* __restrict__ WF,
                                                   unsigned char* __restrict__ hmid8,
                                                   float* __restrict__ attn_sel) {
  __shared__ float As[4][16 * 17 + 2];
  const int tid = threadIdx.x;
  const int wave = tid >> 6, lane = tid & 63;
  const int b = blockIdx.x * 4 + wave;
  const size_t qb = (size_t)b * 4 * N1_;
  const int hl = lane & 15, qg = lane >> 4;

  // S[n][m] products (fp8-derived qkv: fine, softmax path is insensitive)
  f32x4 accS[4][4] = {};
  f32x4 accSel = {};
#pragma unroll
  for (int ch = 0; ch < 2; ++ch) {
    const int off = ch * 32 + qg * 8;
    short8 qf[4], kf[4];
#pragma unroll
    for (int n = 0; n < 4; ++n)
      qf[n] = *(const short8*)(qkv + qb + (size_t)n * N1_ + 0 + hl * 64 + off);
#pragma unroll
    for (int m = 0; m < 4; ++m)
      kf[m] = *(const short8*)(qkv + qb + (size_t)m * N1_ + 1024 + hl * 64 + off);
#pragma unroll
    for (int n = 0; n < 4; ++n)
#pragma unroll
      for (int m = 0; m < 4; ++m)
        accS[n][m] = __builtin_amdgcn_mfma_f32_16x16x32_bf16(qf[n], kf[m], accS[n][m], 0, 0, 0);
    // accurate attn_sel from bf16 fixup rows
    short8 qs = *(const short8*)(q1 + (size_t)b * 1024 + hl * 64 + off);
    short8 ks = *(const short8*)(k2 + (size_t)b * 1024 + hl * 64 + off);
    accSel = __builtin_amdgcn_mfma_f32_16x16x32_bf16(qs, ks, accSel, 0, 0, 0);
  }

#pragma unroll
  for (int r = 0; r < 4; ++r)
    attn_sel[(size_t)b * 256 + (qg * 4 + r) * 16 + hl] = 1.f / (1.f + __expf(-accSel[r]));

  if ((hl >> 2) == qg) {   // diagonal lanes: per-head softmax + A' = attn.WF
    const int h = hl, rr = h & 3;
    float Sm[4][4];
#pragma unroll
    for (int n = 0; n < 4; ++n)
#pragma unroll
      for (int m = 0; m < 4; ++m) Sm[n][m] = accS[n][m][rr];
#pragma unroll
    for (int n = 0; n < 4; ++n) {
      float lg[4];
#pragma unroll
      for (int p = 0; p < 4; ++p)
        lg[p] = Sm[n][0] * WE[p * 4] + Sm[n][1] * WE[p * 4 + 1] +
                Sm[n][2] * WE[p * 4 + 2] + Sm[n][3] * WE[p * 4 + 3];
      float mx = fmaxf(fmaxf(lg[0], lg[1]), fmaxf(lg[2], lg[3]));
      float e0 = __expf(lg[0] - mx), e1 = __expf(lg[1] - mx);
      float e2 = __expf(lg[2] - mx), e3 = __expf(lg[3] - mx);
      float inv = 1.f / (e0 + e1 + e2 + e3);
      e0 *= inv; e1 *= inv; e2 *= inv; e3 *= inv;
#pragma unroll
      for (int m = 0; m < 4; ++m)
        As[wave][h * 17 + n * 4 + m] =
            e0 * WF[0 * 4 + m] + e1 * WF[1 * 4 + m] + e2 * WF[2 * 4 + m] + e3 * WF[3 * 4 + m];
    }
  }
  __syncthreads();

  {  // out[h,n,d] = sum_m A'[n,m] v[h,m,d]; write hmid as fp8 x32 (scale 122)
    const int h = lane & 15, dg = lane >> 4;
    float Ap[4][4];
#pragma unroll
    for (int n = 0; n < 4; ++n)
#pragma unroll
      for (int m = 0; m < 4; ++m) Ap[n][m] = As[wave][h * 17 + n * 4 + m];

    float outv[4][16] = {};
#pragma unroll
    for (int m = 0; m < 4; ++m) {
      const unsigned short* vp = qkv + qb + (size_t)m * N1_ + 2048 + h * 64 + dg * 16;
      short8 v0 = *(const short8*)(vp);
      short8 v1 = *(const short8*)(vp + 8);
      float vf[16];
#pragma unroll
      for (int j = 0; j < 8; ++j) {
        vf[j] = bf2f((unsigned short)v0[j]);
        vf[8 + j] = bf2f((unsigned short)v1[j]);
      }
#pragma unroll
      for (int n = 0; n < 4; ++n)
#pragma unroll
        for (int d = 0; d < 16; ++d) outv[n][d] += Ap[n][m] * vf[d];
    }
#pragma unroll
    for (int n = 0; n < 4; ++n) {
      int w0 = pk_fp8(outv[n][0] * 32.f, outv[n][1] * 32.f, outv[n][2] * 32.f, outv[n][3] * 32.f);
      int w1 = pk_fp8(outv[n][4] * 32.f, outv[n][5] * 32.f, outv[n][6] * 32.f, outv[n][7] * 32.f);
      int w2 = pk_fp8(outv[n][8] * 32.f, outv[n][9] * 32.f, outv[n][10] * 32.f, outv[n][11] * 32.f);
      int w3 = pk_fp8(outv[n][12] * 32.f, outv[n][13] * 32.f, outv[n][14] * 32.f, outv[n][15] * 32.f);
      *(int4*)(hmid8 + ((size_t)b * 4 + n) * 1024 + h * 64 + dg * 16) = make_int4(w0, w1, w2, w3);
    }
  }
}

// ---- launch ------------------------------------------------------------------
extern "C" void kernel_launch(void* const* d_in, const int* in_sizes, int n_in,
                              void* d_out, int out_size, void* d_ws, size_t ws_size,
                              hipStream_t stream) {
  (void)in_sizes; (void)n_in; (void)out_size; (void)ws_size;
  const float* x      = (const float*)d_in[0];
  const float* W_qkv  = (const float*)d_in[1];
  const float* W_proj = (const float*)d_in[2];
  const float* b_proj = (const float*)d_in[3];
  const float* W_E    = (const float*)d_in[4];
  const float* W_F    = (const float*)d_in[5];

  float* out0 = (float*)d_out;                     // [B,N,C] fp32
  float* out1 = out0 + (size_t)M_ * C_;            // [B,H,H] fp32

  char* ws = (char*)d_ws;
  // Region 0 (201.3 MB): early = xsel(33.5M) + wqkvT_bf(6.3M); later = qkv_bf.
  unsigned short* xsel   = (unsigned short*)(ws);
  unsigned short* wqkvTb = (unsigned short*)(ws + 33554432);
  unsigned short* qkv_bf = (unsigned short*)(ws);               // overwrites after fixup
  unsigned char*  x8     = (unsigned char*)(ws + 201326592);    // 33.5M; hmid8 aliases it
  unsigned char*  hmid8  = x8;
  unsigned char*  wqkvT8 = (unsigned char*)(ws + 234881024);    // 3.1M
  unsigned char*  wproj8 = (unsigned char*)(ws + 238026752);    // 1.0M
  unsigned short* q1k2   = (unsigned short*)(ws + 239075328);   // 33.5M (end 272.6M)

  cast_x_k<<<32768, 256, 0, stream>>>(x, x8, xsel);
  transpose_wqkv_k<<<dim3(96, 32), dim3(32, 8), 0, stream>>>(W_qkv, wqkvTb, wqkvT8);
  cast_wproj_k<<<1024, 256, 0, stream>>>(W_proj, wproj8);

  // accurate rows for attn_sel: q1 (rows 0..8191), k2 (rows 8192..16383)
  gemm_fixup<<<dim3(8, 128), 256, 0, stream>>>(xsel, wqkvTb, q1k2);

  // GEMM1: qkv = x @ W_qkv (MX-fp8; A scale 1.0, B x32 -> scale 122)
  gemm_mx<0><<<dim3(24, 256), 256, 0, stream>>>(x8, wqkvT8, qkv_bf, nullptr, nullptr,
                                                1024, 3072, 127, 122);

  attn_mfma_k<<<B_ / 4, 256, 0, stream>>>(qkv_bf, q1k2, q1k2 + (size_t)8192 * 1024,
                                          W_E, W_F, hmid8, out1);

  // GEMM2: out = hmid @ W_proj^T + b (both fp8 x32 -> scales 122,122)
  gemm_mx<1><<<dim3(8, 256), 256, 0, stream>>>(hmid8, wproj8, nullptr, out0, b_proj,
                                               1024, 1024, 122, 122);
}